// Round 14
// baseline (753.265 us; speedup 1.0000x reference)
//
#include <hip/hip_runtime.h>
#include <hip/hip_bf16.h>
#include <hip/hip_fp16.h>
#include <cstdint>
#include <cstddef>

#define NB   131072   // items
#define ED   256      // e_dim
#define NQL  4        // levels
#define NEC  256      // codebook entries

typedef _Float16 f16;
typedef f16  f16x8 __attribute__((ext_vector_type(8)));
typedef float f32x4 __attribute__((ext_vector_type(4)));

static constexpr float FMAXV = 3.402823466e+38f;
static constexpr float TAUH  = 0.078125f;   // rescore gate, d/2 units

static constexpr size_t OFF_REC  = (size_t)NB * ED;
static constexpr size_t OFF_LOSS = 2 * (size_t)NB * ED;
static constexpr size_t OFF_SIDX = OFF_LOSS + 1;
static constexpr size_t OFF_RIDX = OFF_SIDX + (size_t)NB * NQL;

// workspace layout (bytes)
static constexpr size_t WS_LOSS = 0;                      // 8 doubles
static constexpr size_t WS_NORM = 256;                    // 8*256 f32 (norm - 256)
static constexpr size_t WS_CBH  = 256 + 8 * 256 * 4;      // 8448; 8*256*256 f16 (1 MB)

// ---- prep: zero loss accumulators + codebook row norms (pre-shifted by -256) ----
__global__ void kPrep(const float* __restrict__ cbS, const float* __restrict__ cbR,
                      float* __restrict__ norms, double* __restrict__ lossAcc) {
  const int cbi = blockIdx.x;    // 0..7
  const int j   = threadIdx.x;   // 0..255
  if (cbi == 0 && j < 8) lossAcc[j] = 0.0;
  const float* row = (cbi < 4 ? cbS : cbR) + ((size_t)(cbi & 3) * NEC + j) * ED;
  float acc = 0.f;
  for (int k = 0; k < ED; k += 4) {
    float4 v = *(const float4*)(row + k);
    acc += v.x * v.x + v.y * v.y + v.z * v.z + v.w * v.w;
  }
  norms[cbi * NEC + j] = acc - 256.0f;   // exact shift (Sterbenz range)
}

// ---- NEGATED f16 copy of codebooks: acc = 0.5*nrm + sum(-c)*r = d/2 ----
__global__ void kConvH(const float* __restrict__ cbS, const float* __restrict__ cbR,
                       f16* __restrict__ cbH) {
  const int f   = blockIdx.x * 256 + threadIdx.x;   // 0..524287
  const int cbi = f >> 16;
  const int rem = f & 65535;
  const float v = (cbi < 4 ? cbS + ((size_t)cbi << 16) : cbR + ((size_t)(cbi - 4) << 16))[rem];
  cbH[f] = (f16)(-v);   // RTN, negated
}

// packed key helpers: low 8 mantissa bits carry the codeword index
__device__ __forceinline__ float pk(float v, int j) {
  return __uint_as_float((__float_as_uint(v) & ~255u) | (unsigned)j);
}
__device__ __forceinline__ float unpv(float k) {
  return __uint_as_float(__float_as_uint(k) & ~255u);
}
__device__ __forceinline__ void ins3(float& s0, float& s1, float& s2, float k) {
  float t0 = fmaxf(s0, k); s0 = fminf(s0, k);
  float t1 = fmaxf(s1, t0); s1 = fminf(s1, t0);
  s2 = fminf(s2, t1);
}
__device__ __forceinline__ void mrg3(float& a0, float& a1, float& a2,
                                     float b0, float b1, float b2) {
  float x  = fmaxf(a0, b0);
  float c0 = fminf(a0, b0);
  float m1 = fminf(a1, b1), M1 = fmaxf(a1, b1);
  float c1 = fminf(fminf(x, a1), b1);
  float c2 = fminf(fminf(fmaxf(x, m1), M1), fminf(a2, b2));
  a0 = c0; a1 = c1; a2 = c2;
}

// ---- main fused RVQ kernel: DUAL-CHAIN blocks ----
// 32 real items x 2 branches = 64 virtual rows per block (rows 0-31 src,
// 32-63 rec). GEMM keeps r6's dense 16-MFMA batches (mt0-1 x B_src, mt2-3 x
// B_rec); fold/merge/rescore/update each carry TWO independent dependency
// chains in one instruction stream -> serial-section latency serves 2x work.
// d/2 trick (0.5*nrm acc init, negated cbH); setprio around MFMA clusters.
__global__ __launch_bounds__(256, 2)
void kMain(const float* __restrict__ x,
           const float* __restrict__ cbS,
           const float* __restrict__ cbR,
           const f16*  __restrict__ cbH,
           const float* __restrict__ norms,
           double* __restrict__ lossAcc,
           float* __restrict__ out) {
  __shared__ __align__(16) char  RhBuf[64 * 512];      // 64 virtual rows (32 KB)
  __shared__ __align__(16) float keybuf[64][4][4];     // per-wave top-3 per virtual item
  __shared__ float redS[4];

  const int tid   = threadIdx.x;
  const int lane  = tid & 63;
  const int w     = tid >> 6;       // wave: owns codewords [64w, 64w+64)
  const int it_o  = tid >> 2;       // owned VIRTUAL item 0..63
  const int kq    = tid & 3;        // owner k-quarter
  const int vbr   = it_o >> 5;      // branch of owned virtual item
  const int item  = it_o & 31;      // real item 0..31
  const int b0    = blockIdx.x * 32;
  const int l15   = lane & 15;
  const int l4    = lane >> 4;

  const float* cbf32base = vbr ? cbR : cbS;
  float res[64];
  float lossA = 0.f, lossB = 0.f;

  // ---- load residual = x[b0+item, vbr*E + kq*64 ...) into registers ----
  {
    const float* xp = x + (size_t)(b0 + item) * (2 * ED) + vbr * ED + kq * 64;
#pragma unroll
    for (int i = 0; i < 16; ++i) {
      float4 v = *(const float4*)(xp + 4 * i);
      res[4 * i + 0] = v.x; res[4 * i + 1] = v.y;
      res[4 * i + 2] = v.z; res[4 * i + 3] = v.w;
    }
  }

#pragma unroll 1
  for (int lev = 0; lev < NQL; ++lev) {
    const float* nrmS = norms + (size_t)lev * NEC;
    const float* nrmR = norms + (size_t)(4 + lev) * NEC;
    const f16*   cbhS = cbH + ((size_t)lev << 16);
    const f16*   cbhR = cbH + ((size_t)(4 + lev) << 16);
    const float* nrmO  = vbr ? nrmR : nrmS;                    // own branch
    const float* cbf32 = cbf32base + (size_t)lev * NEC * ED;   // own branch fp32

    // ---- stage res -> Rh (f16, RTN), swizzled rows of 512B ----
#pragma unroll
    for (int c = 0; c < 8; ++c) {
      f16x8 h;
#pragma unroll
      for (int u = 0; u < 8; ++u) h[u] = (f16)res[c * 8 + u];
      int off = it_o * 512 + kq * 128 + c * 16;
      off ^= (it_o & 7) << 4;
      *(f16x8*)&RhBuf[off] = h;
    }
    __syncthreads();   // barrier 1: Rh ready

    // ---- acc init = 0.5*nrm of the row's branch -> acc_final = d/2 ----
    f32x4 acc[4][4];
#pragma unroll
    for (int nt = 0; nt < 4; ++nt) {
      float4 nS = *(const float4*)&nrmS[w * 64 + nt * 16 + l4 * 4];
      float4 nR = *(const float4*)&nrmR[w * 64 + nt * 16 + l4 * 4];
      f32x4 hS; hS[0] = 0.5f * nS.x; hS[1] = 0.5f * nS.y; hS[2] = 0.5f * nS.z; hS[3] = 0.5f * nS.w;
      f32x4 hR; hR[0] = 0.5f * nR.x; hR[1] = 0.5f * nR.y; hR[2] = 0.5f * nR.z; hR[3] = 0.5f * nR.w;
      acc[0][nt] = hS; acc[1][nt] = hS;
      acc[2][nt] = hR; acc[3][nt] = hR;
    }

    // ---- GEMM: 64 virtual rows x 64 j per wave; mt0-1 src, mt2-3 rec ----
#pragma unroll 2
    for (int ks = 0; ks < 8; ++ks) {
      f16x8 A[4], Bs[4], Br[4];
#pragma unroll
      for (int mt = 0; mt < 4; ++mt) {
        const int it = mt * 16 + l15;
        // XOR on the FULL offset (matches write side) — do not hoist.
        const int offA = (it * 512 + ks * 64 + l4 * 16) ^ ((it & 7) << 4);
        A[mt] = *(const f16x8*)&RhBuf[offA];
      }
#pragma unroll
      for (int nt = 0; nt < 4; ++nt) {
        const int j = w * 64 + nt * 16 + l15;
        Bs[nt] = *(const f16x8*)&cbhS[(size_t)j * ED + ks * 32 + l4 * 8];
        Br[nt] = *(const f16x8*)&cbhR[(size_t)j * ED + ks * 32 + l4 * 8];
      }
      __builtin_amdgcn_s_setprio(1);
#pragma unroll
      for (int nt = 0; nt < 4; ++nt) {
        acc[0][nt] = __builtin_amdgcn_mfma_f32_16x16x32_f16(Bs[nt], A[0], acc[0][nt], 0, 0, 0);
        acc[1][nt] = __builtin_amdgcn_mfma_f32_16x16x32_f16(Bs[nt], A[1], acc[1][nt], 0, 0, 0);
        acc[2][nt] = __builtin_amdgcn_mfma_f32_16x16x32_f16(Br[nt], A[2], acc[2][nt], 0, 0, 0);
        acc[3][nt] = __builtin_amdgcn_mfma_f32_16x16x32_f16(Br[nt], A[3], acc[3][nt], 0, 0, 0);
      }
      __builtin_amdgcn_s_setprio(0);
    }

    // ---- argmin fold: lane holds 16 j-keys (nt x r) for virtual item mt*16+l15 ----
#pragma unroll
    for (int mt = 0; mt < 4; ++mt) {
      float s0 = FMAXV, s1 = FMAXV, s2 = FMAXV;
#pragma unroll
      for (int nt = 0; nt < 4; ++nt)
#pragma unroll
        for (int r = 0; r < 4; ++r)
          ins3(s0, s1, s2, pk(acc[mt][nt][r], w * 64 + nt * 16 + l4 * 4 + r));
      // merge the 4 l4-groups (disjoint j-subsets, same item): xor 16, 32
      {
        float b0k = __shfl_xor(s0, 16), b1k = __shfl_xor(s1, 16), b2k = __shfl_xor(s2, 16);
        mrg3(s0, s1, s2, b0k, b1k, b2k);
        b0k = __shfl_xor(s0, 32); b1k = __shfl_xor(s1, 32); b2k = __shfl_xor(s2, 32);
        mrg3(s0, s1, s2, b0k, b1k, b2k);
      }
      if (l4 == 0) {   // lanes 0..15 write virtual item mt*16+l15
        float4 v; v.x = s0; v.y = s1; v.z = s2; v.w = FMAXV;
        *(float4*)&keybuf[mt * 16 + l15][w][0] = v;
      }
    }
    __syncthreads();   // barrier 2: keybuf ready (also: all Rh reads done)

    // ---- cross-wave merge in the owner quad (per virtual item) ----
    int jm;
    {
      float4 v = *(const float4*)&keybuf[it_o][kq][0];
      float s0 = v.x, s1 = v.y, s2 = v.z;
      {
        float b0k = __shfl_xor(s0, 1), b1k = __shfl_xor(s1, 1), b2k = __shfl_xor(s2, 1);
        mrg3(s0, s1, s2, b0k, b1k, b2k);
        b0k = __shfl_xor(s0, 2); b1k = __shfl_xor(s1, 2); b2k = __shfl_xor(s2, 2);
        mrg3(s0, s1, s2, b0k, b1k, b2k);
      }
      jm = (int)(__float_as_uint(s0) & 255u);
      const float gap = unpv(s1) - unpv(s0);   // d/2 scale
      if (gap < TAUH) {   // quad-uniform: exact fp32 rescore of top-3 (own branch)
        const int cand[3] = { jm, (int)(__float_as_uint(s1) & 255u),
                                  (int)(__float_as_uint(s2) & 255u) };
        float bestd = FMAXV; int bestj = 0;
#pragma unroll 1
        for (int cc = 0; cc < 3; ++cc) {
          const int j = cand[cc];
          const float* row = cbf32 + (size_t)j * ED + kq * 64;
          float p2 = 0.f;
#pragma unroll
          for (int i = 0; i < 16; ++i) {
            float4 q = *(const float4*)(row + 4 * i);
            p2 = fmaf(res[4 * i + 0], q.x, p2);
            p2 = fmaf(res[4 * i + 1], q.y, p2);
            p2 = fmaf(res[4 * i + 2], q.z, p2);
            p2 = fmaf(res[4 * i + 3], q.w, p2);
          }
          p2 += __shfl_xor(p2, 1);
          p2 += __shfl_xor(p2, 2);
          const float d = fmaf(-2.f, p2, nrmO[j]);
          if (d < bestd || (d == bestd && j < bestj)) { bestd = d; bestj = j; }
        }
        jm = bestj;
      }
      if (kq == 0) {
        const size_t ioff = (vbr ? OFF_RIDX : OFF_SIDX) + (size_t)(b0 + item) * NQL + lev;
        out[ioff] = (float)jm;
      }
    }

    // ---- residual update + loss (exact reference rounding chain) ----
    {
      const float* crow = cbf32 + (size_t)jm * ED + kq * 64;
#pragma unroll
      for (int i = 0; i < 16; ++i) {
        float4 q = *(const float4*)(crow + 4 * i);
#pragma unroll
        for (int u = 0; u < 4; ++u) {
          float cv = (u == 0 ? q.x : u == 1 ? q.y : u == 2 ? q.z : q.w);
          float r  = res[4 * i + u];
          float dd = cv - r;
          if (u & 1) lossB = fmaf(dd, dd, lossB);
          else       lossA = fmaf(dd, dd, lossA);
          float xr = r + dd;      // straight-through x_res
          res[4 * i + u] = r - xr;
        }
      }
    }
  }

  // ---- x_q = x - res_final ----
  {
    const float* xp = x + (size_t)(b0 + item) * (2 * ED) + vbr * ED + kq * 64;
    float* op = out + (vbr ? OFF_REC : 0) + (size_t)(b0 + item) * ED + kq * 64;
#pragma unroll
    for (int i = 0; i < 16; ++i) {
      float4 xv = *(const float4*)(xp + 4 * i);
      float4 o;
      o.x = xv.x - res[4 * i + 0];
      o.y = xv.y - res[4 * i + 1];
      o.z = xv.z - res[4 * i + 2];
      o.w = xv.w - res[4 * i + 3];
      *(float4*)(op + 4 * i) = o;
    }
  }

  // ---- loss: one wave-reduce + one atomic per block (8 slots) ----
  float lossReg = lossA + lossB;
#pragma unroll
  for (int d = 1; d < 64; d <<= 1) lossReg += __shfl_xor(lossReg, d);
  if (lane == 0) redS[w] = lossReg;
  __syncthreads();
  if (tid == 0)
    atomicAdd(&lossAcc[blockIdx.x & 7], (double)((redS[0] + redS[1]) + (redS[2] + redS[3])));
}

// ---- finalize scalar loss ----
__global__ void kFin(const double* __restrict__ lossAcc, float* __restrict__ out) {
  if (blockIdx.x == 0 && threadIdx.x == 0) {
    double s = 0.0;
    for (int l = 0; l < 8; ++l) s += lossAcc[l];
    out[OFF_LOSS] = (float)(s * 1.25 / ((double)NB * ED) / 8.0);
  }
}

extern "C" void kernel_launch(void* const* d_in, const int* in_sizes, int n_in,
                              void* d_out, int out_size, void* d_ws, size_t ws_size,
                              hipStream_t stream) {
  const float* x   = (const float*)d_in[0];
  const float* cbS = (const float*)d_in[1];
  const float* cbR = (const float*)d_in[2];
  float* out = (float*)d_out;
  char*  ws  = (char*)d_ws;

  double* lossAcc = (double*)(ws + WS_LOSS);
  float*  norms   = (float*)(ws + WS_NORM);
  f16*    cbH     = (f16*)(ws + WS_CBH);

  hipLaunchKernelGGL(kPrep,  dim3(8),    dim3(256), 0, stream, cbS, cbR, norms, lossAcc);
  hipLaunchKernelGGL(kConvH, dim3(2048), dim3(256), 0, stream, cbS, cbR, cbH);
  hipLaunchKernelGGL(kMain,  dim3(NB / 32), dim3(256), 0, stream,
                     x, cbS, cbR, cbH, norms, lossAcc, out);
  hipLaunchKernelGGL(kFin,   dim3(1),    dim3(64),  0, stream, lossAcc, out);
}

// Round 15
// 566.435 us; speedup vs baseline: 1.3298x; 1.3298x over previous
//
#include <hip/hip_runtime.h>
#include <hip/hip_bf16.h>
#include <hip/hip_fp16.h>
#include <cstdint>
#include <cstddef>

#define NB   131072   // items
#define ED   256      // e_dim
#define NQL  4        // levels
#define NEC  256      // codebook entries

typedef _Float16 f16;
typedef f16  f16x8 __attribute__((ext_vector_type(8)));
typedef float f32x4 __attribute__((ext_vector_type(4)));

static constexpr float FMAXV = 3.402823466e+38f;
static constexpr float TAUH  = 0.078125f;   // rescore gate, d/2 units

static constexpr size_t OFF_REC  = (size_t)NB * ED;
static constexpr size_t OFF_LOSS = 2 * (size_t)NB * ED;
static constexpr size_t OFF_SIDX = OFF_LOSS + 1;
static constexpr size_t OFF_RIDX = OFF_SIDX + (size_t)NB * NQL;

// workspace layout (bytes)
static constexpr size_t WS_LOSS = 0;                      // 8 doubles
static constexpr size_t WS_NORM = 256;                    // 8*256 f32 (norm - 256)
static constexpr size_t WS_CBH  = 256 + 8 * 256 * 4;      // 8448; 8*256*256 f16 (1 MB)

// ---- prep: zero loss accumulators + codebook row norms (pre-shifted by -256) ----
__global__ void kPrep(const float* __restrict__ cbS, const float* __restrict__ cbR,
                      float* __restrict__ norms, double* __restrict__ lossAcc) {
  const int cbi = blockIdx.x;    // 0..7
  const int j   = threadIdx.x;   // 0..255
  if (cbi == 0 && j < 8) lossAcc[j] = 0.0;
  const float* row = (cbi < 4 ? cbS : cbR) + ((size_t)(cbi & 3) * NEC + j) * ED;
  float acc = 0.f;
  for (int k = 0; k < ED; k += 4) {
    float4 v = *(const float4*)(row + k);
    acc += v.x * v.x + v.y * v.y + v.z * v.z + v.w * v.w;
  }
  norms[cbi * NEC + j] = acc - 256.0f;   // exact shift (Sterbenz range)
}

// ---- NEGATED f16 copy of codebooks: acc = 0.5*nrm + sum(-c)*r = d/2 ----
__global__ void kConvH(const float* __restrict__ cbS, const float* __restrict__ cbR,
                       f16* __restrict__ cbH) {
  const int f   = blockIdx.x * 256 + threadIdx.x;   // 0..524287
  const int cbi = f >> 16;
  const int rem = f & 65535;
  const float v = (cbi < 4 ? cbS + ((size_t)cbi << 16) : cbR + ((size_t)(cbi - 4) << 16))[rem];
  cbH[f] = (f16)(-v);   // RTN, negated
}

// packed key helpers: low 8 mantissa bits carry the codeword index
__device__ __forceinline__ float pk(float v, int j) {
  return __uint_as_float((__float_as_uint(v) & ~255u) | (unsigned)j);
}
__device__ __forceinline__ float unpv(float k) {
  return __uint_as_float(__float_as_uint(k) & ~255u);
}
__device__ __forceinline__ void ins3(float& s0, float& s1, float& s2, float k) {
  float t0 = fmaxf(s0, k); s0 = fminf(s0, k);
  float t1 = fmaxf(s1, t0); s1 = fminf(s1, t0);
  s2 = fminf(s2, t1);
}
__device__ __forceinline__ void mrg3(float& a0, float& a1, float& a2,
                                     float b0, float b1, float b2) {
  float x  = fmaxf(a0, b0);
  float c0 = fminf(a0, b0);
  float m1 = fminf(a1, b1), M1 = fmaxf(a1, b1);
  float c1 = fminf(fminf(x, a1), b1);
  float c2 = fminf(fminf(fmaxf(x, m1), M1), fminf(a2, b2));
  a0 = c0; a1 = c1; a2 = c2;
}

// ---- main fused RVQ kernel: r13 structure + pre-barrier prefetch ----
// 64 items/block, 4 waves, acc[4][4] (8 loads : 16 MFMA — the measured density
// optimum: r7/r8/r9/r12/r14 all regressed on worse ratios). Branch-split
// blocks (gridDim.y=2). d/2 trick. NEW: B0 + nrm/acc-init issue BEFORE
// barrier 1 (Rh-independent) so each level's GEMM starts with loads in
// flight; 4-way loss chains in the update.
__global__ __launch_bounds__(256, 2)
void kMain(const float* __restrict__ x,
           const float* __restrict__ cbS,
           const float* __restrict__ cbR,
           const f16*  __restrict__ cbH,
           const float* __restrict__ norms,
           double* __restrict__ lossAcc,
           float* __restrict__ out) {
  __shared__ __align__(16) char  RhBuf[64 * 512];      // f16 residual image (32 KB)
  __shared__ __align__(16) float keybuf[64][4][4];     // per-wave top-3 per item (4 KB)
  __shared__ float redS[4];

  const int tid   = threadIdx.x;
  const int lane  = tid & 63;
  const int w     = tid >> 6;       // wave: owns codewords [64w, 64w+64)
  const int it_o  = tid >> 2;       // owner item 0..63
  const int kq    = tid & 3;        // owner k-quarter
  const int b0    = blockIdx.x * 64;
  const int br    = blockIdx.y;     // branch (src/rec) — one 4-level chain/block
  const int l15   = lane & 15;
  const int l4    = lane >> 4;

  const float* cbf32base = br ? cbR : cbS;
  float res[64];
  float lossA = 0.f, lossB = 0.f, lossC = 0.f, lossD = 0.f;

  // ---- load residual = x[:, br*E .. br*E+E) slice into registers ----
  {
    const float* xp = x + (size_t)(b0 + it_o) * (2 * ED) + br * ED + kq * 64;
#pragma unroll
    for (int i = 0; i < 16; ++i) {
      float4 v = *(const float4*)(xp + 4 * i);
      res[4 * i + 0] = v.x; res[4 * i + 1] = v.y;
      res[4 * i + 2] = v.z; res[4 * i + 3] = v.w;
    }
  }

#pragma unroll 1
  for (int lev = 0; lev < NQL; ++lev) {
    const int cbi = br * 4 + lev;
    const float* nrm = norms + (size_t)cbi * NEC;
    const f16*   cbh = cbH + ((size_t)cbi << 16);
    const float* cbf32 = cbf32base + (size_t)lev * NEC * ED;

    // ---- stage res -> Rh (f16, RTN), swizzled rows of 512B ----
#pragma unroll
    for (int c = 0; c < 8; ++c) {
      f16x8 h;
#pragma unroll
      for (int u = 0; u < 8; ++u) h[u] = (f16)res[c * 8 + u];
      int off = it_o * 512 + kq * 128 + c * 16;
      off ^= (it_o & 7) << 4;
      *(f16x8*)&RhBuf[off] = h;
    }

    // ---- PRE-BARRIER (Rh-independent): acc init from nrm + first B batch ----
    f32x4 acc[4][4];
#pragma unroll
    for (int nt = 0; nt < 4; ++nt) {
      float4 nv = *(const float4*)&nrm[w * 64 + nt * 16 + l4 * 4];
      f32x4 h; h[0] = 0.5f * nv.x; h[1] = 0.5f * nv.y;
      h[2] = 0.5f * nv.z; h[3] = 0.5f * nv.w;
#pragma unroll
      for (int mt = 0; mt < 4; ++mt) acc[mt][nt] = h;
    }

    f16x8 A0[4], B0[4], A1[4], B1[4];
#define LOADA(Adst, ks_)                                                        \
    {                                                                           \
      _Pragma("unroll")                                                         \
      for (int mt = 0; mt < 4; ++mt) {                                          \
        const int it = mt * 16 + l15;                                           \
        const int offA = (it * 512 + (ks_) * 64 + l4 * 16) ^ ((it & 7) << 4);   \
        Adst[mt] = *(const f16x8*)&RhBuf[offA];                                 \
      }                                                                         \
    }
#define LOADB(Bdst, ks_)                                                        \
    {                                                                           \
      _Pragma("unroll")                                                         \
      for (int nt = 0; nt < 4; ++nt) {                                          \
        const int j = w * 64 + nt * 16 + l15;                                   \
        Bdst[nt] = *(const f16x8*)&cbh[(size_t)j * ED + (ks_) * 32 + l4 * 8];   \
      }                                                                         \
    }
#define MFMA16(Aop, Bop)                                                        \
    {                                                                           \
      __builtin_amdgcn_s_setprio(1);                                            \
      _Pragma("unroll")                                                         \
      for (int mt = 0; mt < 4; ++mt)                                            \
        _Pragma("unroll")                                                       \
        for (int nt = 0; nt < 4; ++nt)                                          \
          acc[mt][nt] = __builtin_amdgcn_mfma_f32_16x16x32_f16(                 \
              Bop[nt], Aop[mt], acc[mt][nt], 0, 0, 0);                          \
      __builtin_amdgcn_s_setprio(0);                                            \
    }

    LOADB(B0, 0);        // in flight across the barrier
    __syncthreads();     // barrier 1: Rh ready
    LOADA(A0, 0);
#pragma unroll 1
    for (int ks2 = 0; ks2 < 4; ++ks2) {
      LOADA(A1, 2 * ks2 + 1); LOADB(B1, 2 * ks2 + 1);   // issue next batch first
      MFMA16(A0, B0);
      if (ks2 < 3) { LOADA(A0, 2 * ks2 + 2); LOADB(B0, 2 * ks2 + 2); }
      MFMA16(A1, B1);
    }
#undef LOADA
#undef LOADB
#undef MFMA16

    // ---- argmin: lane holds 16 j-keys (nt x r) for item = mt*16+l15 ----
#pragma unroll
    for (int mt = 0; mt < 4; ++mt) {
      float s0 = FMAXV, s1 = FMAXV, s2 = FMAXV;
#pragma unroll
      for (int nt = 0; nt < 4; ++nt)
#pragma unroll
        for (int r = 0; r < 4; ++r)
          ins3(s0, s1, s2, pk(acc[mt][nt][r], w * 64 + nt * 16 + l4 * 4 + r));
      // merge the 4 l4-groups (disjoint j-subsets, same item): xor 16, 32
      {
        float b0k = __shfl_xor(s0, 16), b1k = __shfl_xor(s1, 16), b2k = __shfl_xor(s2, 16);
        mrg3(s0, s1, s2, b0k, b1k, b2k);
        b0k = __shfl_xor(s0, 32); b1k = __shfl_xor(s1, 32); b2k = __shfl_xor(s2, 32);
        mrg3(s0, s1, s2, b0k, b1k, b2k);
      }
      if (l4 == 0) {   // lanes 0..15 write item mt*16+l15
        float4 v; v.x = s0; v.y = s1; v.z = s2; v.w = FMAXV;
        *(float4*)&keybuf[mt * 16 + l15][w][0] = v;
      }
    }
    __syncthreads();   // barrier 2: keybuf ready (also: all Rh reads done)

    // ---- cross-wave merge in the owner quad ----
    int jm;
    {
      float4 v = *(const float4*)&keybuf[it_o][kq][0];
      float s0 = v.x, s1 = v.y, s2 = v.z;
      {
        float b0k = __shfl_xor(s0, 1), b1k = __shfl_xor(s1, 1), b2k = __shfl_xor(s2, 1);
        mrg3(s0, s1, s2, b0k, b1k, b2k);
        b0k = __shfl_xor(s0, 2); b1k = __shfl_xor(s1, 2); b2k = __shfl_xor(s2, 2);
        mrg3(s0, s1, s2, b0k, b1k, b2k);
      }
      jm = (int)(__float_as_uint(s0) & 255u);
      const float gap = unpv(s1) - unpv(s0);   // d/2 scale
      if (gap < TAUH) {   // quad-uniform: exact fp32 rescore of top-3
        const int cand[3] = { jm, (int)(__float_as_uint(s1) & 255u),
                                  (int)(__float_as_uint(s2) & 255u) };
        float bestd = FMAXV; int bestj = 0;
#pragma unroll 1
        for (int cc = 0; cc < 3; ++cc) {
          const int j = cand[cc];
          const float* row = cbf32 + (size_t)j * ED + kq * 64;
          float p2 = 0.f;
#pragma unroll
          for (int i = 0; i < 16; ++i) {
            float4 q = *(const float4*)(row + 4 * i);
            p2 = fmaf(res[4 * i + 0], q.x, p2);
            p2 = fmaf(res[4 * i + 1], q.y, p2);
            p2 = fmaf(res[4 * i + 2], q.z, p2);
            p2 = fmaf(res[4 * i + 3], q.w, p2);
          }
          p2 += __shfl_xor(p2, 1);
          p2 += __shfl_xor(p2, 2);
          const float d = fmaf(-2.f, p2, nrm[j]);
          if (d < bestd || (d == bestd && j < bestj)) { bestd = d; bestj = j; }
        }
        jm = bestj;
      }
      if (kq == 0) {
        const size_t ioff = (br ? OFF_RIDX : OFF_SIDX) + (size_t)(b0 + it_o) * NQL + lev;
        out[ioff] = (float)jm;
      }
    }

    // ---- residual update + loss (exact chain; 4 independent loss chains) ----
    {
      const float* crow = cbf32 + (size_t)jm * ED + kq * 64;
#pragma unroll
      for (int i = 0; i < 16; ++i) {
        float4 q = *(const float4*)(crow + 4 * i);
#pragma unroll
        for (int u = 0; u < 4; ++u) {
          float cv = (u == 0 ? q.x : u == 1 ? q.y : u == 2 ? q.z : q.w);
          float r  = res[4 * i + u];
          float dd = cv - r;
          if      (u == 0) lossA = fmaf(dd, dd, lossA);
          else if (u == 1) lossB = fmaf(dd, dd, lossB);
          else if (u == 2) lossC = fmaf(dd, dd, lossC);
          else             lossD = fmaf(dd, dd, lossD);
          float xr = r + dd;      // straight-through x_res
          res[4 * i + u] = r - xr;
        }
      }
    }
  }

  // ---- x_q = x - res_final ----
  {
    const float* xp = x + (size_t)(b0 + it_o) * (2 * ED) + br * ED + kq * 64;
    float* op = out + (br ? OFF_REC : 0) + (size_t)(b0 + it_o) * ED + kq * 64;
#pragma unroll
    for (int i = 0; i < 16; ++i) {
      float4 xv = *(const float4*)(xp + 4 * i);
      float4 o;
      o.x = xv.x - res[4 * i + 0];
      o.y = xv.y - res[4 * i + 1];
      o.z = xv.z - res[4 * i + 2];
      o.w = xv.w - res[4 * i + 3];
      *(float4*)(op + 4 * i) = o;
    }
  }

  // ---- loss: one wave-reduce + one atomic per block (8 slots) ----
  float lossReg = (lossA + lossB) + (lossC + lossD);
#pragma unroll
  for (int d = 1; d < 64; d <<= 1) lossReg += __shfl_xor(lossReg, d);
  if (lane == 0) redS[w] = lossReg;
  __syncthreads();
  if (tid == 0)
    atomicAdd(&lossAcc[blockIdx.x & 7], (double)((redS[0] + redS[1]) + (redS[2] + redS[3])));
}

// ---- finalize scalar loss ----
__global__ void kFin(const double* __restrict__ lossAcc, float* __restrict__ out) {
  if (blockIdx.x == 0 && threadIdx.x == 0) {
    double s = 0.0;
    for (int l = 0; l < 8; ++l) s += lossAcc[l];
    out[OFF_LOSS] = (float)(s * 1.25 / ((double)NB * ED) / 8.0);
  }
}

extern "C" void kernel_launch(void* const* d_in, const int* in_sizes, int n_in,
                              void* d_out, int out_size, void* d_ws, size_t ws_size,
                              hipStream_t stream) {
  const float* x   = (const float*)d_in[0];
  const float* cbS = (const float*)d_in[1];
  const float* cbR = (const float*)d_in[2];
  float* out = (float*)d_out;
  char*  ws  = (char*)d_ws;

  double* lossAcc = (double*)(ws + WS_LOSS);
  float*  norms   = (float*)(ws + WS_NORM);
  f16*    cbH     = (f16*)(ws + WS_CBH);

  hipLaunchKernelGGL(kPrep,  dim3(8),    dim3(256), 0, stream, cbS, cbR, norms, lossAcc);
  hipLaunchKernelGGL(kConvH, dim3(2048), dim3(256), 0, stream, cbS, cbR, cbH);
  hipLaunchKernelGGL(kMain,  dim3(NB / 64, 2), dim3(256), 0, stream,
                     x, cbS, cbR, cbH, norms, lossAcc, out);
  hipLaunchKernelGGL(kFin,   dim3(1),    dim3(64),  0, stream, lossAcc, out);
}